// Round 3
// baseline (133.136 us; speedup 1.0000x reference)
//
#include <hip/hip_runtime.h>
#include <hip/hip_bf16.h>

// SimilarityPreserving loss via row-sums only:
//   loss = (1/b^2) * sum_i [ A/sa^2 + B/sb^2 - 2C/(sa*sb) ]
//   A_i = sum_j ct(i,j)^2, B_i = sum_j cs(i,j)^2, C_i = sum_j ct*cs
// ct/cs = cosine grams over row-normalized inputs (bf16 MFMA, fp32 acc).
// Temperature cancels in row-normalization; eps never binds. Sim matrices
// never materialized.
//
// Round-3 gram structure:
//  - block = 128 rows x 64 cols per step, 4 waves in 2x2 -> wave tile 64x32.
//    A (s+t) in 128 VGPRs/wave, loaded once. Halves LDS B-read redundancy
//    vs round 2 (was 4 waves x full column sweep).
//  - double-buffered 32 KB tiles (64 KB LDS/block, 2 blocks/CU), loop =
//    { barrier; stage(t+1 -> other buf); compute(t) }: the DMA drain at the
//    next barrier has a full compute phase to complete -> ~zero exposed
//    latency (vs fully-exposed drain in round 2).
//  - per-(grp,row) partial slots instead of atomics; no memset dispatch.

typedef __attribute__((ext_vector_type(8))) short short8;   // 8 bf16 = 4 VGPRs
typedef __attribute__((ext_vector_type(4))) float float4v;  // MFMA C/D

#define BSZ 8192
#define DIM 128
#define NGRP 8    // grid.x: column groups (1024 cols each)
#define STEPS 16  // 64-col tiles per group

__device__ __forceinline__ void async_ld16(void* lds, const void* g) {
    __builtin_amdgcn_global_load_lds(
        (const __attribute__((address_space(1))) void*)g,
        (__attribute__((address_space(3))) void*)lds, 16, 0, 0);
}

// ---------------------------------------------------------------- normalize
__global__ __launch_bounds__(256) void normalize_all(
    const float* __restrict__ x0, const float* __restrict__ x1,
    const float* __restrict__ x2, const float* __restrict__ x3,
    __hip_bfloat16* __restrict__ out)
{
    int gw   = (blockIdx.x * 256 + threadIdx.x) >> 6;  // global wave = row id
    int lane = threadIdx.x & 63;
    int mat  = gw >> 13;           // 0..3
    int row  = gw & (BSZ - 1);
    const float* in = (mat == 0) ? x0 : (mat == 1) ? x1 : (mat == 2) ? x2 : x3;

    const float2* rp = (const float2*)(in + (size_t)row * DIM);
    float2 v = rp[lane];
    float ss = v.x * v.x + v.y * v.y;
    #pragma unroll
    for (int off = 1; off < 64; off <<= 1) ss += __shfl_xor(ss, off);
    float nrm = sqrtf(ss);
    float inv = nrm > 0.f ? 1.f / nrm : 0.f;

    __hip_bfloat162* op = (__hip_bfloat162*)(out + ((size_t)mat * BSZ + row) * DIM);
    __hip_bfloat162 o;
    o.x = __float2bfloat16(v.x * inv);
    o.y = __float2bfloat16(v.y * inv);
    op[lane] = o;
}

// ---------------------------------------------------------------- dual gram
__global__ __launch_bounds__(256, 2) void gram_kernel(
    const __hip_bfloat16* __restrict__ Xs, const __hip_bfloat16* __restrict__ Ys,
    const __hip_bfloat16* __restrict__ Xt, const __hip_bfloat16* __restrict__ Yt,
    float* __restrict__ pA, float* __restrict__ pB, float* __restrict__ pC)
{
    // [buf][mat][chunk]: 64-col x 128-K tile, 1024 16B-chunks per mat = 64 KB
    __shared__ short8 lds[2][2][1024];

    const int tid  = threadIdx.x;
    const int lane = tid & 63;
    const int wave = tid >> 6;
    const int wr = wave & 1;    // 64-row half
    const int wc = wave >> 1;   // 32-col half
    const int q  = lane >> 4;
    const int l15 = lane & 15;
    const int strip = blockIdx.y;  // 0..63
    const int grp   = blockIdx.x;  // 0..NGRP-1

    // A fragments: wave rows strip*128 + wr*64 + rb*16 + l15 (rb 0..3)
    // MFMA A layout: lane holds A[m=l15][k=q*8+j] -> short8 chunk kk*4+q.
    short8 as[4][4], at[4][4];
    {
        const int rbase = strip * 128 + wr * 64;
        #pragma unroll
        for (int rb = 0; rb < 4; ++rb) {
            int row = rbase + rb * 16 + l15;
            const short8* xs = (const short8*)(Xs + (size_t)row * DIM);
            const short8* xt = (const short8*)(Xt + (size_t)row * DIM);
            #pragma unroll
            for (int kk = 0; kk < 4; ++kk) {
                as[rb][kk] = xs[kk * 4 + q];
                at[rb][kk] = xt[kk * 4 + q];
            }
        }
    }

    float4v pa[4], pb[4], pc[4];
    #pragma unroll
    for (int rb = 0; rb < 4; ++rb) {
        pa[rb] = (float4v){0.f, 0.f, 0.f, 0.f};
        pb[rb] = pa[rb];
        pc[rb] = pa[rb];
    }

    const short8* gYs = (const short8*)Ys;
    const short8* gYt = (const short8*)Yt;

    // stage column tile ct (64 gram-cols = 64 rows of Y) into buffer buf.
    // LDS chunk s holds global chunk (row<<4) + (sc ^ (row&7)) — swizzle on
    // the GLOBAL side (LDS side must stay linear for global_load_lds).
    auto stage = [&](int buf, int ct) {
        const short8* gs = gYs + (size_t)ct * 1024;
        const short8* gt = gYt + (size_t)ct * 1024;
        #pragma unroll
        for (int it = 0; it < 4; ++it) {
            int s   = it * 256 + tid;     // 0..1023
            int row = s >> 4, sc = s & 15;
            int g   = (row << 4) + (sc ^ (row & 7));
            async_ld16(&lds[buf][0][s], &gs[g]);
            async_ld16(&lds[buf][1][s], &gt[g]);
        }
    };

    stage(0, grp * STEPS);

    for (int t = 0; t < STEPS; ++t) {
        __syncthreads();  // drains DMA(buf t&1) — issued a full compute ago
        if (t + 1 < STEPS) stage((t + 1) & 1, grp * STEPS + t + 1);

        const short8* ls = lds[t & 1][0];
        const short8* lt = lds[t & 1][1];

        #pragma unroll
        for (int cb = 0; cb < 2; ++cb) {
            int col = wc * 32 + cb * 16 + l15;  // local col 0..63
            short8 bs[4], bt[4];
            #pragma unroll
            for (int kk = 0; kk < 4; ++kk) {
                int chunk = (col << 4) + ((kk * 4 + q) ^ (col & 7));
                bs[kk] = ls[chunk];
                bt[kk] = lt[chunk];
            }
            #pragma unroll
            for (int rb = 0; rb < 4; ++rb) {
                float4v ds = {0.f, 0.f, 0.f, 0.f}, dt = ds;
                #pragma unroll
                for (int kk = 0; kk < 4; ++kk) {
                    ds = __builtin_amdgcn_mfma_f32_16x16x32_bf16(as[rb][kk], bs[kk], ds, 0, 0, 0);
                    dt = __builtin_amdgcn_mfma_f32_16x16x32_bf16(at[rb][kk], bt[kk], dt, 0, 0, 0);
                }
                #pragma unroll
                for (int r = 0; r < 4; ++r) {
                    pa[rb][r] += dt[r] * dt[r];
                    pb[rb][r] += ds[r] * ds[r];
                    pc[rb][r] += dt[r] * ds[r];
                }
            }
        }
    }

    // Epilogue: D row = q*4 + r, col = l15. Reduce over the 16 lanes of each
    // quad-group; write per-group partial slot (no atomics).
    #pragma unroll
    for (int rb = 0; rb < 4; ++rb) {
        #pragma unroll
        for (int r = 0; r < 4; ++r) {
            float va = pa[rb][r], vb = pb[rb][r], vc = pc[rb][r];
            #pragma unroll
            for (int off = 1; off < 16; off <<= 1) {
                va += __shfl_xor(va, off);
                vb += __shfl_xor(vb, off);
                vc += __shfl_xor(vc, off);
            }
            if (l15 == 0) {
                int row = strip * 128 + wr * 64 + rb * 16 + q * 4 + r;
                size_t slot = (size_t)grp * BSZ + row;
                pA[slot] = va;
                pB[slot] = vb;
                pC[slot] = vc;
            }
        }
    }
}

// ---------------------------------------------------------------- finalize
__global__ __launch_bounds__(1024) void finalize_kernel(
    const float* __restrict__ pA, const float* __restrict__ pB,
    const float* __restrict__ pC, float* __restrict__ out)
{
    __shared__ float red[16];
    float acc = 0.f;
    for (int i = threadIdx.x; i < BSZ; i += 1024) {
        float a = 0.f, b = 0.f, c = 0.f;
        #pragma unroll
        for (int g = 0; g < NGRP; ++g) {
            a += pA[(size_t)g * BSZ + i];
            b += pB[(size_t)g * BSZ + i];
            c += pC[(size_t)g * BSZ + i];
        }
        float sa = fmaxf(sqrtf(a), 1e-12f);  // NORM_EPS
        float sb = fmaxf(sqrtf(b), 1e-12f);
        acc += a / (sa * sa) + b / (sb * sb) - 2.f * c / (sa * sb);
    }
    #pragma unroll
    for (int off = 1; off < 64; off <<= 1) acc += __shfl_xor(acc, off);
    int wv = threadIdx.x >> 6, lane = threadIdx.x & 63;
    if (lane == 0) red[wv] = acc;
    __syncthreads();
    if (threadIdx.x == 0) {
        float s = 0.f;
        #pragma unroll
        for (int w = 0; w < 16; ++w) s += red[w];
        out[0] = s / ((float)BSZ * (float)BSZ);
    }
}

// ---------------------------------------------------------------- launch
extern "C" void kernel_launch(void* const* d_in, const int* in_sizes, int n_in,
                              void* d_out, int out_size, void* d_ws, size_t ws_size,
                              hipStream_t stream) {
    const float* zxs = (const float*)d_in[0];
    const float* zys = (const float*)d_in[1];
    const float* zxt = (const float*)d_in[2];
    const float* zyt = (const float*)d_in[3];
    // d_in[4] = temperature: cancels exactly, unused.
    float* out = (float*)d_out;

    char* ws = (char*)d_ws;
    __hip_bfloat16* nXs = (__hip_bfloat16*)ws;
    __hip_bfloat16* nYs = nXs + (size_t)BSZ * DIM;
    __hip_bfloat16* nXt = nYs + (size_t)BSZ * DIM;
    __hip_bfloat16* nYt = nXt + (size_t)BSZ * DIM;
    float* pA = (float*)(ws + 4 * (size_t)BSZ * DIM * sizeof(__hip_bfloat16));
    float* pB = pA + (size_t)NGRP * BSZ;
    float* pC = pB + (size_t)NGRP * BSZ;

    normalize_all<<<(4 * BSZ) / 4, 256, 0, stream>>>(zxs, zys, zxt, zyt, nXs);

    dim3 grid(NGRP, BSZ / 128);  // 8 x 64 = 512 blocks = 2/CU
    gram_kernel<<<grid, 256, 0, stream>>>(nXs, nYs, nXt, nYt, pA, pB, pC);

    finalize_kernel<<<1, 1024, 0, stream>>>(pA, pB, pC, out);
}